// Round 1
// baseline (479.016 us; speedup 1.0000x reference)
//
#include <hip/hip_runtime.h>

// FinePreprocess: gather 5x5 windows (stride 4, pad 2) from two NCHW fp32
// feature maps at M random (batch, grid-idx) points.
// Output flat layout (per map): (M, C, 5, 5) — the reference's final
// reshape(M,25,C) is a view, memory order is (m, c, r, col).

#define MPTS 6000
#define NCH  128
#define FH   240
#define FW   320
#define OUTW 80          // (320 + 2*2 - 5)/4 + 1
#define MAPSZ (MPTS * NCH * 25)   // 19,200,000 floats per map

__global__ __launch_bounds__(256) void fine_gather_kernel(
    const float* __restrict__ f0, const float* __restrict__ f1,
    const int* __restrict__ b_ids, const int* __restrict__ i_ids,
    const int* __restrict__ j_ids, float* __restrict__ out)
{
    const int total = 2 * MPTS * NCH * 5;   // one thread per (map, m, c, r)
    int tid = blockIdx.x * 256 + threadIdx.x;
    if (tid >= total) return;

    int r   = tid % 5;
    int t1  = tid / 5;
    int c   = t1 % NCH;
    int t2  = t1 / NCH;
    int m   = t2 % MPTS;
    int map = t2 / MPTS;

    int b   = b_ids[m];
    int idx = map ? j_ids[m] : i_ids[m];
    const float* feat = map ? f1 : f0;

    int gy = idx / OUTW;
    int gx = idx - gy * OUTW;
    int row  = gy * 4 + r - 2;     // original (unpadded) coords
    int col0 = gx * 4 - 2;

    bool vrow = (row >= 0) && (row < FH);
    const float* src = feat + (((long)(b * NCH + c) * FH + row) * FW + col0);

    long opos = (long)map * MAPSZ + ((long)(m * NCH + c) * 5 + r) * 5;

    float v[5];
#pragma unroll
    for (int k = 0; k < 5; k++) {
        int cc = col0 + k;
        bool ok = vrow && (cc >= 0) && (cc < FW);
        v[k] = ok ? src[k] : 0.0f;
    }
#pragma unroll
    for (int k = 0; k < 5; k++) out[opos + k] = v[k];
}

extern "C" void kernel_launch(void* const* d_in, const int* in_sizes, int n_in,
                              void* d_out, int out_size, void* d_ws, size_t ws_size,
                              hipStream_t stream) {
    const float* f0   = (const float*)d_in[0];
    const float* f1   = (const float*)d_in[1];
    // d_in[2] = hw0_f, d_in[3] = hw0_c — compile-time constants here, unused
    const int* b_ids  = (const int*)d_in[4];
    const int* i_ids  = (const int*)d_in[5];
    const int* j_ids  = (const int*)d_in[6];
    float* out        = (float*)d_out;

    const int total  = 2 * MPTS * NCH * 5;       // 7,680,000 threads
    const int blocks = (total + 255) / 256;      // 30,000 blocks
    fine_gather_kernel<<<blocks, 256, 0, stream>>>(f0, f1, b_ids, i_ids, j_ids, out);
}

// Round 2
// 438.205 us; speedup vs baseline: 1.0931x; 1.0931x over previous
//
#include <hip/hip_runtime.h>

// FinePreprocess: gather 5x5 windows (stride 4, pad 2) from two NCHW fp32
// feature maps at M random (batch, grid-idx) points.
// Output flat layout (per map): (M, C, 5, 5) — reference's reshape(M,25,C) is
// a view of (M, C*25); memory order is (m, c, r, col).
//
// R2: request-throughput attack. R1 was L2-request-bound (~0.52 req/cyc/CU):
//   - loads: 20-B segments are 8-B aligned (col0 even, rows 1280-B aligned)
//     -> float2+float2+float = ~3.2 line-requests/segment instead of 5.
//   - stores: stage the 12.8 KB per-point tile in LDS, store coalesced
//     float4 -> 200 requests/point instead of 3200.

#define MPTS 6000
#define NCH  128
#define FH   240
#define FW   320
#define OUTW 80                 // (320 + 2*2 - 5)/4 + 1
#define PTFLOATS (NCH * 25)     // 3200 floats = 12.8 KB per (map, point)

typedef float f2 __attribute__((ext_vector_type(2)));  // naturally 8-B aligned

__global__ __launch_bounds__(320) void fine_gather_kernel(
    const float* __restrict__ f0, const float* __restrict__ f1,
    const int* __restrict__ b_ids, const int* __restrict__ i_ids,
    const int* __restrict__ j_ids, float* __restrict__ out)
{
    __shared__ __align__(16) float lds[PTFLOATS];

    const int blk = blockIdx.x;            // 0 .. 2*MPTS-1
    const int map = blk >= MPTS;
    const int m   = map ? blk - MPTS : blk;
    const float* __restrict__ feat = map ? f1 : f0;
    const int idx = map ? j_ids[m] : i_ids[m];
    const int b   = b_ids[m];

    const int gy = idx / OUTW;
    const int gx = idx - gy * OUTW;
    const int row0 = gy * 4 - 2;           // top row of window (may be -2,-1)
    const int col0 = gx * 4 - 2;           // left col (even; OOB only if gx==0)

    const int t = threadIdx.x;

    // Phase 1: gather 640 segments (c=0..127, r=0..4), 2 per thread.
    // Segment s -> c = s/5, r = s%5; 5 contiguous floats at (row0+r, col0..col0+4).
    // Max col touched: 79*4-2+4 = 318 < 320, so only the LEFT edge can be OOB.
#pragma unroll
    for (int it = 0; it < 2; it++) {
        const int s = t + it * 320;
        const int c = s / 5;
        const int r = s - c * 5;
        const int row = row0 + r;
        const bool vrow = (row >= 0) & (row < FH);
        const float* src = feat + (((long)(b * NCH + c) * FH + row) * FW + col0);

        float v[5];
        if (vrow && (col0 >= 0)) {
            // fast path: 8-B-aligned vector loads (col0*4 is a multiple of 8)
            const f2* p = (const f2*)src;
            f2 a0 = p[0];
            f2 a1 = p[1];
            v[0] = a0.x; v[1] = a0.y; v[2] = a1.x; v[3] = a1.y;
            v[4] = src[4];
        } else {
#pragma unroll
            for (int k = 0; k < 5; k++) {
                const int cc = col0 + k;
                v[k] = (vrow && cc >= 0) ? src[k] : 0.0f;
            }
        }
        const int base = s * 5;            // (c*5 + r) * 5
#pragma unroll
        for (int k = 0; k < 5; k++) lds[base + k] = v[k];
    }

    __syncthreads();

    // Phase 2: coalesced float4 store of the 12.8 KB tile.
    float4* __restrict__ dst = (float4*)(out + (long)blk * PTFLOATS);
    const float4* sl = (const float4*)lds;
    for (int i = t; i < PTFLOATS / 4; i += 320)   // 800 float4s, 2-3 per thread
        dst[i] = sl[i];
}

extern "C" void kernel_launch(void* const* d_in, const int* in_sizes, int n_in,
                              void* d_out, int out_size, void* d_ws, size_t ws_size,
                              hipStream_t stream) {
    const float* f0   = (const float*)d_in[0];
    const float* f1   = (const float*)d_in[1];
    // d_in[2] = hw0_f, d_in[3] = hw0_c — compile-time constants, unused
    const int* b_ids  = (const int*)d_in[4];
    const int* i_ids  = (const int*)d_in[5];
    const int* j_ids  = (const int*)d_in[6];
    float* out        = (float*)d_out;

    fine_gather_kernel<<<2 * MPTS, 320, 0, stream>>>(f0, f1, b_ids, i_ids, j_ids, out);
}